// Round 3
// baseline (783.787 us; speedup 1.0000x reference)
//
#include <hip/hip_runtime.h>
#include <stdint.h>

// GNN layer, fp32, CSR-restructured (no hot-path atomics, no LDS broadcast):
//   A = nf @ We[:,0:64]^T; B = nf @ We[:,64:128]^T      (K1, wave-per-node)
//   CSR build: hist -> scan -> scatter  (incidence list: node v <- (u, e))
//   red[v] = sum_{(u,e) in inc(v)} leaky(A[u] + B[v] + ef[e]@We[:,128:160]^T)
//   out = leaky(nf @ Wn[:,0:64]^T + red @ Wn[:,64:128]^T)
// Wave-uniform row addresses over const __restrict__ memory -> scalar s_load
// broadcasts; per-lane weights in VGPRs (lane = output channel).

#define LEAKY(x) ((x) > 0.0f ? (x) : 0.01f * (x))

static __device__ __forceinline__ int rfl(int x) {
    return __builtin_amdgcn_readfirstlane(x);
}

// ---------------- K1: A,B = nf @ [Wsrc|Wdst]^T ----------------
// wave-per-(node,half); half = wave_id & 1 is loop-invariant (stride even).
__global__ __launch_bounds__(256) void node_ab_kernel(
    const float* __restrict__ nf, const float* __restrict__ We,
    float* __restrict__ A, float* __restrict__ B, int N)
{
    const int lane = threadIdx.x & 63;
    const int gw = blockIdx.x * 4 + rfl(threadIdx.x >> 6);
    const int W = gridDim.x * 4;
    const int half = gw & 1;
    float* __restrict__ out = half ? B : A;

    float4 w[16];
    {
        const float4* wr = (const float4*)(We + lane * 160 + half * 64);
        #pragma unroll
        for (int k = 0; k < 16; ++k) w[k] = wr[k];
    }

    for (int v = gw >> 1; v < N; v += (W >> 1)) {
        const float* m = nf + (size_t)v * 64;      // wave-uniform
        float a0 = 0.f, a1 = 0.f, a2 = 0.f, a3 = 0.f;
        #pragma unroll
        for (int k = 0; k < 16; ++k) {
            a0 += m[4 * k + 0] * w[k].x;
            a1 += m[4 * k + 1] * w[k].y;
            a2 += m[4 * k + 2] * w[k].z;
            a3 += m[4 * k + 3] * w[k].w;
        }
        out[(size_t)v * 64 + lane] = (a0 + a1) + (a2 + a3);
    }
}

// ---------------- CSR build ----------------
__global__ void hist_kernel(const int* __restrict__ src, const int* __restrict__ dst,
                            int* __restrict__ cnt, int E)
{
    int i = blockIdx.x * blockDim.x + threadIdx.x;
    const int stride = gridDim.x * blockDim.x;
    for (; i < E; i += stride) {
        atomicAdd(&cnt[dst[i]], 1);
        atomicAdd(&cnt[src[i]], 1);
    }
}

// chunk = 512 elements per block of 256 threads.
__global__ __launch_bounds__(256) void scan_a_kernel(
    const int* __restrict__ cnt, int* __restrict__ row, int* __restrict__ sums, int N)
{
    __shared__ int ls[256];
    const int t = threadIdx.x;
    const int base = blockIdx.x * 512;
    const int g0 = base + 2 * t, g1 = g0 + 1;
    const int x0 = (g0 < N) ? cnt[g0] : 0;
    const int x1 = (g1 < N) ? cnt[g1] : 0;
    const int s = x0 + x1;
    ls[t] = s;
    __syncthreads();
    #pragma unroll
    for (int off = 1; off < 256; off <<= 1) {
        int v = (t >= off) ? ls[t - off] : 0;
        __syncthreads();
        ls[t] += v;
        __syncthreads();
    }
    const int excl = ls[t] - s;
    if (g0 < N) row[g0] = excl;
    if (g1 < N) row[g1] = excl + x0;
    if (t == 255) sums[blockIdx.x] = ls[t];
}

__global__ __launch_bounds__(256) void scan_b_kernel(int* __restrict__ sums, int nb)
{
    __shared__ int ls[256];
    const int t = threadIdx.x;
    const int s = (t < nb) ? sums[t] : 0;
    ls[t] = s;
    __syncthreads();
    #pragma unroll
    for (int off = 1; off < 256; off <<= 1) {
        int v = (t >= off) ? ls[t - off] : 0;
        __syncthreads();
        ls[t] += v;
        __syncthreads();
    }
    if (t < nb) sums[t] = ls[t] - s;   // exclusive, in place
}

__global__ void scan_c_kernel(int* __restrict__ row, int* __restrict__ ofs,
                              const int* __restrict__ sums, int N, int total)
{
    const int i = blockIdx.x * blockDim.x + threadIdx.x;
    if (i < N) {
        const int r = row[i] + sums[i >> 9];
        row[i] = r;
        ofs[i] = r;
    }
    if (i == 0) row[N] = total;
}

__global__ void scatter_kernel(const int* __restrict__ src, const int* __restrict__ dst,
                               int* __restrict__ ofs, int2* __restrict__ inc, int E)
{
    int i = blockIdx.x * blockDim.x + threadIdx.x;
    const int stride = gridDim.x * blockDim.x;
    for (; i < E; i += stride) {
        const int s = src[i], d = dst[i];
        const int p = atomicAdd(&ofs[d], 1);
        inc[p] = make_int2(s, i);          // message into d from source s
        const int q = atomicAdd(&ofs[s], 1);
        inc[q] = make_int2(d, i);          // reverse message into s
    }
}

// ---------------- reduce: red[v] = sum leaky(A[u]+B[v]+C[e]) ----------------
__global__ __launch_bounds__(256) void reduce_kernel(
    const float* __restrict__ A, const float* __restrict__ B,
    const float* __restrict__ ef, const float* __restrict__ We,
    const int* __restrict__ row, const int2* __restrict__ inc,
    float* __restrict__ red, int N)
{
    const int lane = threadIdx.x & 63;
    const int gw = blockIdx.x * 4 + rfl(threadIdx.x >> 6);
    const int W = gridDim.x * 4;

    float4 w[8];
    {
        const float4* wr = (const float4*)(We + lane * 160 + 128);
        #pragma unroll
        for (int k = 0; k < 8; ++k) w[k] = wr[k];
    }

    for (int v = gw; v < N; v += W) {
        const float b = B[(size_t)v * 64 + lane];
        const int beg = row[v], end = row[v + 1];     // wave-uniform
        float acc = 0.f;
        for (int i = beg; i < end; ++i) {
            const int2 r = inc[i];                    // all lanes same i
            const int u = rfl(r.x), e = rfl(r.y);     // force uniform
            const float a = A[(size_t)u * 64 + lane]; // coalesced 256B gather
            const float* efr = ef + (size_t)e * 32;   // wave-uniform row
            float c0 = 0.f, c1 = 0.f, c2 = 0.f, c3 = 0.f;
            #pragma unroll
            for (int k = 0; k < 8; ++k) {
                c0 += efr[4 * k + 0] * w[k].x;
                c1 += efr[4 * k + 1] * w[k].y;
                c2 += efr[4 * k + 2] * w[k].z;
                c3 += efr[4 * k + 3] * w[k].w;
            }
            const float m = a + b + ((c0 + c1) + (c2 + c3));
            acc += LEAKY(m);
        }
        red[(size_t)v * 64 + lane] = acc;
    }
}

// ---------------- apply: out = leaky(nf@Wn1^T + red@Wn2^T) ----------------
__global__ __launch_bounds__(256) void apply_kernel(
    const float* __restrict__ nf, const float* __restrict__ red,
    const float* __restrict__ Wn, float* __restrict__ out, int N)
{
    const int lane = threadIdx.x & 63;
    const int gw = blockIdx.x * 4 + rfl(threadIdx.x >> 6);
    const int W = gridDim.x * 4;

    float4 w1[16], w2[16];
    {
        const float4* wr = (const float4*)(Wn + lane * 128);
        #pragma unroll
        for (int k = 0; k < 16; ++k) w1[k] = wr[k];
        #pragma unroll
        for (int k = 0; k < 16; ++k) w2[k] = wr[16 + k];
    }

    for (int v = gw; v < N; v += W) {
        const float* m1 = nf + (size_t)v * 64;    // wave-uniform
        const float* m2 = red + (size_t)v * 64;   // wave-uniform
        float a0 = 0.f, a1 = 0.f, a2 = 0.f, a3 = 0.f;
        #pragma unroll
        for (int k = 0; k < 16; ++k) {
            a0 += m1[4 * k + 0] * w1[k].x;
            a1 += m1[4 * k + 1] * w1[k].y;
            a2 += m1[4 * k + 2] * w1[k].z;
            a3 += m1[4 * k + 3] * w1[k].w;
        }
        #pragma unroll
        for (int k = 0; k < 16; ++k) {
            a0 += m2[4 * k + 0] * w2[k].x;
            a1 += m2[4 * k + 1] * w2[k].y;
            a2 += m2[4 * k + 2] * w2[k].z;
            a3 += m2[4 * k + 3] * w2[k].w;
        }
        const float acc = (a0 + a1) + (a2 + a3);
        out[(size_t)v * 64 + lane] = LEAKY(acc);
    }
}

extern "C" void kernel_launch(void* const* d_in, const int* in_sizes, int n_in,
                              void* d_out, int out_size, void* d_ws, size_t ws_size,
                              hipStream_t stream) {
    const float* nf  = (const float*)d_in[0];   // [N,64]
    const float* ef  = (const float*)d_in[1];   // [E,32]
    const int*   src = (const int*)d_in[2];     // [E]
    const int*   dst = (const int*)d_in[3];     // [E]
    const float* We  = (const float*)d_in[4];   // [64,160]
    const float* Wn  = (const float*)d_in[5];   // [64,128]

    const int N = in_sizes[0] / 64;
    const int E = in_sizes[2];

    // ws layout
    float* A   = (float*)d_ws;                       // N*64
    float* B   = A + (size_t)N * 64;                 // N*64
    float* red = B + (size_t)N * 64;                 // N*64
    int* cnt   = (int*)(red + (size_t)N * 64);       // N
    int* row   = cnt + N;                            // N+1
    int* sums  = row + (N + 1);                      // 256
    int* ofs   = sums + 256;                         // N
    int2* inc  = (int2*)(((uintptr_t)(ofs + N) + 15) & ~(uintptr_t)15);  // 2E

    hipMemsetAsync(cnt, 0, (size_t)N * sizeof(int), stream);
    node_ab_kernel<<<2048, 256, 0, stream>>>(nf, We, A, B, N);
    hist_kernel<<<1024, 256, 0, stream>>>(src, dst, cnt, E);
    const int nb = (N + 511) / 512;   // 196 <= 256
    scan_a_kernel<<<nb, 256, 0, stream>>>(cnt, row, sums, N);
    scan_b_kernel<<<1, 256, 0, stream>>>(sums, nb);
    scan_c_kernel<<<(N + 255) / 256, 256, 0, stream>>>(row, ofs, sums, N, 2 * E);
    scatter_kernel<<<1024, 256, 0, stream>>>(src, dst, ofs, inc, E);
    reduce_kernel<<<2048, 256, 0, stream>>>(A, B, ef, We, row, inc, red, N);
    apply_kernel<<<2048, 256, 0, stream>>>(nf, red, Wn, (float*)d_out, N);
}

// Round 4
// 442.379 us; speedup vs baseline: 1.7718x; 1.7718x over previous
//
#include <hip/hip_runtime.h>
#include <stdint.h>

// GNN layer, fp32, GEMM-restructured + CSR reduce:
//   prep: transpose weights into WT_ab[64][128], WT_c[32][64], WT_n[128][64]
//   gemm_ab: [A16|B16] = nf @ We[:,0:128]^T          (fp16 out, [N,64] each)
//   gemm_c:  C16 = ef @ We[:,128:160]^T              (fp16 out, [E,64])
//   CSR build: hist -> scan -> scatter  (incidence (u,e) per destination v)
//   reduce:  red[v] = sum leaky(A16[u] + B16[v] + C16[e])   (fp32)
//   apply:   out = leaky(nf @ Wn[:,0:64]^T + red @ Wn[:,64:128]^T)
// GEMMs: 128-row tiles, K LDS-resident, 8x8 / 8x4 register blocking,
// XOR-swizzled transposed A-tile (conflict-free staging + reads).

#define LEAKY(x) ((x) > 0.0f ? (x) : 0.01f * (x))
typedef _Float16 f16;

// swizzled index into a [K][128] LDS tile: XOR on bits 2..4 of the column,
// keyed by k>>2 -> transposed staging writes and float4 reads both ~2-way max.
static __device__ __forceinline__ int swz(int k, int c) {
    return k * 128 + (c ^ (((k >> 2) & 7) << 2));
}

union H4 { f16 h[4]; short4 s; };

// ---------------- weight prep (transpose into ws) ----------------
__global__ void prep_weights_kernel(const float* __restrict__ We,
                                    const float* __restrict__ Wn,
                                    float* __restrict__ WTab,
                                    float* __restrict__ WTc,
                                    float* __restrict__ WTn)
{
    int i = blockIdx.x * blockDim.x + threadIdx.x;
    const int stride = gridDim.x * blockDim.x;
    for (; i < 8192 + 2048 + 8192; i += stride) {
        if (i < 8192) {
            int k = i >> 7, n = i & 127;
            WTab[i] = We[(n & 63) * 160 + (n >> 6) * 64 + k];
        } else if (i < 10240) {
            int j = i - 8192; int k = j >> 6, n = j & 63;
            WTc[j] = We[n * 160 + 128 + k];
        } else {
            int j = i - 10240; int k = j >> 6, n = j & 63;
            WTn[j] = Wn[n * 128 + k];
        }
    }
}

// ---------------- gemm_ab: [A|B] = nf @ WT_ab, tile 128x128, K=64 ----------------
__global__ __launch_bounds__(256) void gemm_ab_kernel(
    const float4* __restrict__ nf4, const float* __restrict__ WT,
    f16* __restrict__ A16, f16* __restrict__ B16, int M)
{
    __shared__ float As[64 * 128];
    __shared__ float Ws[64 * 128];
    const int t = threadIdx.x;
    const int tr = t >> 4, tc = t & 15;
    const int m0 = blockIdx.x * 128;

    #pragma unroll
    for (int i = 0; i < 8; ++i)
        ((float4*)Ws)[t + 256 * i] = ((const float4*)WT)[t + 256 * i];
    #pragma unroll
    for (int i = 0; i < 8; ++i) {
        const int idx = t + 256 * i;
        const int m = idx >> 4, kq = idx & 15;
        float4 v = make_float4(0.f, 0.f, 0.f, 0.f);
        if (m0 + m < M) v = nf4[(size_t)(m0 + m) * 16 + kq];
        As[swz(4 * kq + 0, m)] = v.x;
        As[swz(4 * kq + 1, m)] = v.y;
        As[swz(4 * kq + 2, m)] = v.z;
        As[swz(4 * kq + 3, m)] = v.w;
    }
    __syncthreads();

    float acc[8][8];
    #pragma unroll
    for (int ri = 0; ri < 8; ++ri)
        #pragma unroll
        for (int ci = 0; ci < 8; ++ci) acc[ri][ci] = 0.f;

    #pragma unroll 8
    for (int k = 0; k < 64; ++k) {
        const float4 aLo = *(const float4*)&As[swz(k, tr * 4)];
        const float4 aHi = *(const float4*)&As[swz(k, 64 + tr * 4)];
        const float4 bLo = *(const float4*)&Ws[k * 128 + tc * 4];
        const float4 bHi = *(const float4*)&Ws[k * 128 + 64 + tc * 4];
        const float av[8] = {aLo.x, aLo.y, aLo.z, aLo.w, aHi.x, aHi.y, aHi.z, aHi.w};
        const float bv[8] = {bLo.x, bLo.y, bLo.z, bLo.w, bHi.x, bHi.y, bHi.z, bHi.w};
        #pragma unroll
        for (int ri = 0; ri < 8; ++ri)
            #pragma unroll
            for (int ci = 0; ci < 8; ++ci) acc[ri][ci] += av[ri] * bv[ci];
    }

    #pragma unroll
    for (int ri = 0; ri < 8; ++ri) {
        const int v = m0 + ((ri < 4) ? (tr * 4 + ri) : (64 + tr * 4 + ri - 4));
        if (v < M) {
            H4 lo, hi;
            #pragma unroll
            for (int j = 0; j < 4; ++j) { lo.h[j] = (f16)acc[ri][j]; hi.h[j] = (f16)acc[ri][4 + j]; }
            *(short4*)&A16[(size_t)v * 64 + tc * 4] = lo.s;
            *(short4*)&B16[(size_t)v * 64 + tc * 4] = hi.s;
        }
    }
}

// ---------------- gemm_c: C = ef @ WT_c, tile 128x64, K=32 ----------------
__global__ __launch_bounds__(256) void gemm_c_kernel(
    const float4* __restrict__ ef4, const float* __restrict__ WT,
    f16* __restrict__ C16, int M)
{
    __shared__ float As[32 * 128];
    __shared__ float Ws[32 * 64];
    const int t = threadIdx.x;
    const int tr = t >> 4, tc = t & 15;
    const int m0 = blockIdx.x * 128;

    #pragma unroll
    for (int i = 0; i < 2; ++i)
        ((float4*)Ws)[t + 256 * i] = ((const float4*)WT)[t + 256 * i];
    #pragma unroll
    for (int i = 0; i < 4; ++i) {
        const int idx = t + 256 * i;
        const int m = idx >> 3, kq = idx & 7;
        float4 v = make_float4(0.f, 0.f, 0.f, 0.f);
        if (m0 + m < M) v = ef4[(size_t)(m0 + m) * 8 + kq];
        As[swz(4 * kq + 0, m)] = v.x;
        As[swz(4 * kq + 1, m)] = v.y;
        As[swz(4 * kq + 2, m)] = v.z;
        As[swz(4 * kq + 3, m)] = v.w;
    }
    __syncthreads();

    float acc[8][4];
    #pragma unroll
    for (int ri = 0; ri < 8; ++ri)
        #pragma unroll
        for (int ci = 0; ci < 4; ++ci) acc[ri][ci] = 0.f;

    #pragma unroll 8
    for (int k = 0; k < 32; ++k) {
        const float4 aLo = *(const float4*)&As[swz(k, tr * 4)];
        const float4 aHi = *(const float4*)&As[swz(k, 64 + tr * 4)];
        const float4 w  = *(const float4*)&Ws[k * 64 + tc * 4];
        const float av[8] = {aLo.x, aLo.y, aLo.z, aLo.w, aHi.x, aHi.y, aHi.z, aHi.w};
        const float bv[4] = {w.x, w.y, w.z, w.w};
        #pragma unroll
        for (int ri = 0; ri < 8; ++ri)
            #pragma unroll
            for (int ci = 0; ci < 4; ++ci) acc[ri][ci] += av[ri] * bv[ci];
    }

    #pragma unroll
    for (int ri = 0; ri < 8; ++ri) {
        const int v = m0 + ((ri < 4) ? (tr * 4 + ri) : (64 + tr * 4 + ri - 4));
        if (v < M) {
            H4 u;
            #pragma unroll
            for (int j = 0; j < 4; ++j) u.h[j] = (f16)acc[ri][j];
            *(short4*)&C16[(size_t)v * 64 + tc * 4] = u.s;
        }
    }
}

// ---------------- CSR build ----------------
__global__ void hist_kernel(const int* __restrict__ src, const int* __restrict__ dst,
                            int* __restrict__ cnt, int E)
{
    int i = blockIdx.x * blockDim.x + threadIdx.x;
    const int stride = gridDim.x * blockDim.x;
    for (; i < E; i += stride) {
        atomicAdd(&cnt[dst[i]], 1);
        atomicAdd(&cnt[src[i]], 1);
    }
}

__global__ __launch_bounds__(256) void scan_a_kernel(
    const int* __restrict__ cnt, int* __restrict__ row, int* __restrict__ sums, int N)
{
    __shared__ int ls[256];
    const int t = threadIdx.x;
    const int base = blockIdx.x * 512;
    const int g0 = base + 2 * t, g1 = g0 + 1;
    const int x0 = (g0 < N) ? cnt[g0] : 0;
    const int x1 = (g1 < N) ? cnt[g1] : 0;
    const int s = x0 + x1;
    ls[t] = s;
    __syncthreads();
    #pragma unroll
    for (int off = 1; off < 256; off <<= 1) {
        int v = (t >= off) ? ls[t - off] : 0;
        __syncthreads();
        ls[t] += v;
        __syncthreads();
    }
    const int excl = ls[t] - s;
    if (g0 < N) row[g0] = excl;
    if (g1 < N) row[g1] = excl + x0;
    if (t == 255) sums[blockIdx.x] = ls[t];
}

__global__ __launch_bounds__(256) void scan_b_kernel(int* __restrict__ sums, int nb)
{
    __shared__ int ls[256];
    const int t = threadIdx.x;
    const int s = (t < nb) ? sums[t] : 0;
    ls[t] = s;
    __syncthreads();
    #pragma unroll
    for (int off = 1; off < 256; off <<= 1) {
        int v = (t >= off) ? ls[t - off] : 0;
        __syncthreads();
        ls[t] += v;
        __syncthreads();
    }
    if (t < nb) sums[t] = ls[t] - s;
}

__global__ void scan_c_kernel(int* __restrict__ row, int* __restrict__ ofs,
                              const int* __restrict__ sums, int N, int total)
{
    const int i = blockIdx.x * blockDim.x + threadIdx.x;
    if (i < N) {
        const int r = row[i] + sums[i >> 9];
        row[i] = r;
        ofs[i] = r;
    }
    if (i == 0) row[N] = total;
}

__global__ void scatter_kernel(const int* __restrict__ src, const int* __restrict__ dst,
                               int* __restrict__ ofs, int2* __restrict__ inc, int E)
{
    int i = blockIdx.x * blockDim.x + threadIdx.x;
    const int stride = gridDim.x * blockDim.x;
    for (; i < E; i += stride) {
        const int s = src[i], d = dst[i];
        const int p = atomicAdd(&ofs[d], 1);
        inc[p] = make_int2(s, i);
        const int q = atomicAdd(&ofs[s], 1);
        inc[q] = make_int2(d, i);
    }
}

// ---------------- reduce: red[v] = sum leaky(A[u]+B[v]+C[e]) ----------------
// Tiny VGPR footprint -> full occupancy; per-lane coalesced 128B gathers.
__global__ __launch_bounds__(256) void reduce_kernel(
    const f16* __restrict__ A16, const f16* __restrict__ B16,
    const f16* __restrict__ C16, const int* __restrict__ row,
    const int2* __restrict__ inc, float* __restrict__ red, int N)
{
    const int lane = threadIdx.x & 63;
    const int gw = (blockIdx.x * blockDim.x + threadIdx.x) >> 6;
    const int W = (gridDim.x * blockDim.x) >> 6;
    for (int v = gw; v < N; v += W) {
        const float b = (float)B16[(size_t)v * 64 + lane];
        int i = row[v];
        const int end = row[v + 1];
        float acc = 0.f;
        if (i < end) {
            int2 r = inc[i];
            for (; i < end; ++i) {
                const int2 rn = inc[i + 1];   // inc padded by 1 entry
                const float a = (float)A16[(size_t)r.x * 64 + lane];
                const float c = (float)C16[(size_t)r.y * 64 + lane];
                const float m = a + b + c;
                acc += LEAKY(m);
                r = rn;
            }
        }
        red[(size_t)v * 64 + lane] = acc;
    }
}

// ---------------- apply: out = leaky([nf|red] @ WT_n), tile 128x64, K=128 ----------------
__global__ __launch_bounds__(256) void apply_kernel(
    const float4* __restrict__ nf4, const float4* __restrict__ red4,
    const float* __restrict__ WT, float* __restrict__ out, int M)
{
    __shared__ float As[64 * 128];
    __shared__ float Ws[128 * 64];
    const int t = threadIdx.x;
    const int tr = t >> 4, tc = t & 15;
    const int m0 = blockIdx.x * 128;

    #pragma unroll
    for (int i = 0; i < 8; ++i)
        ((float4*)Ws)[t + 256 * i] = ((const float4*)WT)[t + 256 * i];

    float acc[8][4];
    #pragma unroll
    for (int ri = 0; ri < 8; ++ri)
        #pragma unroll
        for (int ci = 0; ci < 4; ++ci) acc[ri][ci] = 0.f;

    for (int h = 0; h < 2; ++h) {
        const float4* __restrict__ src = h ? red4 : nf4;
        #pragma unroll
        for (int i = 0; i < 8; ++i) {
            const int idx = t + 256 * i;
            const int m = idx >> 4, kq = idx & 15;
            float4 v = make_float4(0.f, 0.f, 0.f, 0.f);
            if (m0 + m < M) v = src[(size_t)(m0 + m) * 16 + kq];
            As[swz(4 * kq + 0, m)] = v.x;
            As[swz(4 * kq + 1, m)] = v.y;
            As[swz(4 * kq + 2, m)] = v.z;
            As[swz(4 * kq + 3, m)] = v.w;
        }
        __syncthreads();
        #pragma unroll 8
        for (int k = 0; k < 64; ++k) {
            const float4 aLo = *(const float4*)&As[swz(k, tr * 4)];
            const float4 aHi = *(const float4*)&As[swz(k, 64 + tr * 4)];
            const float4 w  = *(const float4*)&Ws[(h * 64 + k) * 64 + tc * 4];
            const float av[8] = {aLo.x, aLo.y, aLo.z, aLo.w, aHi.x, aHi.y, aHi.z, aHi.w};
            const float bv[4] = {w.x, w.y, w.z, w.w};
            #pragma unroll
            for (int ri = 0; ri < 8; ++ri)
                #pragma unroll
                for (int ci = 0; ci < 4; ++ci) acc[ri][ci] += av[ri] * bv[ci];
        }
        __syncthreads();
    }

    #pragma unroll
    for (int ri = 0; ri < 8; ++ri) {
        const int v = m0 + ((ri < 4) ? (tr * 4 + ri) : (64 + tr * 4 + ri - 4));
        if (v < M) {
            float4 o;
            o.x = LEAKY(acc[ri][0]); o.y = LEAKY(acc[ri][1]);
            o.z = LEAKY(acc[ri][2]); o.w = LEAKY(acc[ri][3]);
            *(float4*)&out[(size_t)v * 64 + tc * 4] = o;
        }
    }
}

extern "C" void kernel_launch(void* const* d_in, const int* in_sizes, int n_in,
                              void* d_out, int out_size, void* d_ws, size_t ws_size,
                              hipStream_t stream) {
    const float* nf  = (const float*)d_in[0];   // [N,64]
    const float* ef  = (const float*)d_in[1];   // [E,32]
    const int*   src = (const int*)d_in[2];     // [E]
    const int*   dst = (const int*)d_in[3];     // [E]
    const float* We  = (const float*)d_in[4];   // [64,160]
    const float* Wn  = (const float*)d_in[5];   // [64,128]

    const int N = in_sizes[0] / 64;
    const int E = in_sizes[2];

    char* p = (char*)d_ws;
    auto alloc = [&](size_t bytes) -> char* {
        char* r = p; p += (bytes + 255) & ~(size_t)255; return r;
    };
    float* red  = (float*)alloc((size_t)N * 64 * 4);
    float* WTab = (float*)alloc(8192 * 4);
    float* WTc  = (float*)alloc(2048 * 4);
    float* WTn  = (float*)alloc(8192 * 4);
    int2*  inc  = (int2*)alloc(((size_t)2 * E + 1) * 8);
    int*   cnt  = (int*)alloc((size_t)N * 4);
    int*   row  = (int*)alloc(((size_t)N + 1) * 4);
    int*   sums = (int*)alloc(256 * 4);
    int*   ofs  = (int*)alloc((size_t)N * 4);
    f16*   A16  = (f16*)alloc((size_t)N * 64 * 2);
    f16*   B16  = (f16*)alloc((size_t)N * 64 * 2);
    f16*   C16  = (f16*)alloc((size_t)E * 64 * 2);

    hipMemsetAsync(cnt, 0, (size_t)N * sizeof(int), stream);
    prep_weights_kernel<<<36, 256, 0, stream>>>(We, Wn, WTab, WTc, WTn);
    gemm_ab_kernel<<<(N + 127) / 128, 256, 0, stream>>>((const float4*)nf, WTab, A16, B16, N);
    gemm_c_kernel<<<(E + 127) / 128, 256, 0, stream>>>((const float4*)ef, WTc, C16, E);
    hist_kernel<<<1024, 256, 0, stream>>>(src, dst, cnt, E);
    const int nb = (N + 511) / 512;
    scan_a_kernel<<<nb, 256, 0, stream>>>(cnt, row, sums, N);
    scan_b_kernel<<<1, 256, 0, stream>>>(sums, nb);
    scan_c_kernel<<<(N + 255) / 256, 256, 0, stream>>>(row, ofs, sums, N, 2 * E);
    scatter_kernel<<<1024, 256, 0, stream>>>(src, dst, ofs, inc, E);
    reduce_kernel<<<2048, 256, 0, stream>>>(A16, B16, C16, row, inc, red, N);
    apply_kernel<<<(N + 127) / 128, 256, 0, stream>>>((const float4*)nf, (const float4*)red,
                                                      WTn, (float*)d_out, N);
}

// Round 5
// 380.895 us; speedup vs baseline: 2.0578x; 1.1614x over previous
//
#include <hip/hip_runtime.h>
#include <stdint.h>

// GNN layer, fp32, GEMM-restructured + CSR reduce:
//   prep: transpose weights into WT_ab[64][128], WT_c[32][64], WT_n[128][64]
//   gemm_ab: [A16|B16] = nf @ We[:,0:128]^T          (fp16 out, [N,64] each)
//   gemm_c:  C16 = ef @ We[:,128:160]^T              (fp16 out, [E,64])
//   CSR build: hist -> scan -> scatter  (incidence (u,e) per destination v)
//   reduce:  red[v] = sum leaky(A16[u] + B16[v] + C16[e])   (fp32)
//            unrolled x4, 8 gathers in flight (MLP fix for R4's 1.46 TB/s)
//   apply:   out = leaky(nf @ Wn[:,0:64]^T + red @ Wn[:,64:128]^T)

#define LEAKY(x) ((x) > 0.0f ? (x) : 0.01f * (x))
typedef _Float16 f16;

static __device__ __forceinline__ int swz(int k, int c) {
    return k * 128 + (c ^ (((k >> 2) & 7) << 2));
}

union H4 { f16 h[4]; short4 s; };

// ---------------- weight prep (transpose into ws) ----------------
__global__ void prep_weights_kernel(const float* __restrict__ We,
                                    const float* __restrict__ Wn,
                                    float* __restrict__ WTab,
                                    float* __restrict__ WTc,
                                    float* __restrict__ WTn)
{
    int i = blockIdx.x * blockDim.x + threadIdx.x;
    const int stride = gridDim.x * blockDim.x;
    for (; i < 8192 + 2048 + 8192; i += stride) {
        if (i < 8192) {
            int k = i >> 7, n = i & 127;
            WTab[i] = We[(n & 63) * 160 + (n >> 6) * 64 + k];
        } else if (i < 10240) {
            int j = i - 8192; int k = j >> 6, n = j & 63;
            WTc[j] = We[n * 160 + 128 + k];
        } else {
            int j = i - 10240; int k = j >> 6, n = j & 63;
            WTn[j] = Wn[n * 128 + k];
        }
    }
}

// ---------------- gemm_ab: [A|B] = nf @ WT_ab, tile 128x128, K=64 ----------------
__global__ __launch_bounds__(256) void gemm_ab_kernel(
    const float4* __restrict__ nf4, const float* __restrict__ WT,
    f16* __restrict__ A16, f16* __restrict__ B16, int M)
{
    __shared__ float As[64 * 128];
    __shared__ float Ws[64 * 128];
    const int t = threadIdx.x;
    const int tr = t >> 4, tc = t & 15;
    const int m0 = blockIdx.x * 128;

    #pragma unroll
    for (int i = 0; i < 8; ++i)
        ((float4*)Ws)[t + 256 * i] = ((const float4*)WT)[t + 256 * i];
    #pragma unroll
    for (int i = 0; i < 8; ++i) {
        const int idx = t + 256 * i;
        const int m = idx >> 4, kq = idx & 15;
        float4 v = make_float4(0.f, 0.f, 0.f, 0.f);
        if (m0 + m < M) v = nf4[(size_t)(m0 + m) * 16 + kq];
        As[swz(4 * kq + 0, m)] = v.x;
        As[swz(4 * kq + 1, m)] = v.y;
        As[swz(4 * kq + 2, m)] = v.z;
        As[swz(4 * kq + 3, m)] = v.w;
    }
    __syncthreads();

    float acc[8][8];
    #pragma unroll
    for (int ri = 0; ri < 8; ++ri)
        #pragma unroll
        for (int ci = 0; ci < 8; ++ci) acc[ri][ci] = 0.f;

    #pragma unroll 8
    for (int k = 0; k < 64; ++k) {
        const float4 aLo = *(const float4*)&As[swz(k, tr * 4)];
        const float4 aHi = *(const float4*)&As[swz(k, 64 + tr * 4)];
        const float4 bLo = *(const float4*)&Ws[k * 128 + tc * 4];
        const float4 bHi = *(const float4*)&Ws[k * 128 + 64 + tc * 4];
        const float av[8] = {aLo.x, aLo.y, aLo.z, aLo.w, aHi.x, aHi.y, aHi.z, aHi.w};
        const float bv[8] = {bLo.x, bLo.y, bLo.z, bLo.w, bHi.x, bHi.y, bHi.z, bHi.w};
        #pragma unroll
        for (int ri = 0; ri < 8; ++ri)
            #pragma unroll
            for (int ci = 0; ci < 8; ++ci) acc[ri][ci] += av[ri] * bv[ci];
    }

    #pragma unroll
    for (int ri = 0; ri < 8; ++ri) {
        const int v = m0 + ((ri < 4) ? (tr * 4 + ri) : (64 + tr * 4 + ri - 4));
        if (v < M) {
            H4 lo, hi;
            #pragma unroll
            for (int j = 0; j < 4; ++j) { lo.h[j] = (f16)acc[ri][j]; hi.h[j] = (f16)acc[ri][4 + j]; }
            *(short4*)&A16[(size_t)v * 64 + tc * 4] = lo.s;
            *(short4*)&B16[(size_t)v * 64 + tc * 4] = hi.s;
        }
    }
}

// ---------------- gemm_c: C = ef @ WT_c, tile 128x64, K=32 ----------------
__global__ __launch_bounds__(256) void gemm_c_kernel(
    const float4* __restrict__ ef4, const float* __restrict__ WT,
    f16* __restrict__ C16, int M)
{
    __shared__ float As[32 * 128];
    __shared__ float Ws[32 * 64];
    const int t = threadIdx.x;
    const int tr = t >> 4, tc = t & 15;
    const int m0 = blockIdx.x * 128;

    #pragma unroll
    for (int i = 0; i < 2; ++i)
        ((float4*)Ws)[t + 256 * i] = ((const float4*)WT)[t + 256 * i];
    #pragma unroll
    for (int i = 0; i < 4; ++i) {
        const int idx = t + 256 * i;
        const int m = idx >> 3, kq = idx & 7;
        float4 v = make_float4(0.f, 0.f, 0.f, 0.f);
        if (m0 + m < M) v = ef4[(size_t)(m0 + m) * 8 + kq];
        As[swz(4 * kq + 0, m)] = v.x;
        As[swz(4 * kq + 1, m)] = v.y;
        As[swz(4 * kq + 2, m)] = v.z;
        As[swz(4 * kq + 3, m)] = v.w;
    }
    __syncthreads();

    float acc[8][4];
    #pragma unroll
    for (int ri = 0; ri < 8; ++ri)
        #pragma unroll
        for (int ci = 0; ci < 4; ++ci) acc[ri][ci] = 0.f;

    #pragma unroll 8
    for (int k = 0; k < 32; ++k) {
        const float4 aLo = *(const float4*)&As[swz(k, tr * 4)];
        const float4 aHi = *(const float4*)&As[swz(k, 64 + tr * 4)];
        const float4 w  = *(const float4*)&Ws[k * 64 + tc * 4];
        const float av[8] = {aLo.x, aLo.y, aLo.z, aLo.w, aHi.x, aHi.y, aHi.z, aHi.w};
        const float bv[4] = {w.x, w.y, w.z, w.w};
        #pragma unroll
        for (int ri = 0; ri < 8; ++ri)
            #pragma unroll
            for (int ci = 0; ci < 4; ++ci) acc[ri][ci] += av[ri] * bv[ci];
    }

    #pragma unroll
    for (int ri = 0; ri < 8; ++ri) {
        const int v = m0 + ((ri < 4) ? (tr * 4 + ri) : (64 + tr * 4 + ri - 4));
        if (v < M) {
            H4 u;
            #pragma unroll
            for (int j = 0; j < 4; ++j) u.h[j] = (f16)acc[ri][j];
            *(short4*)&C16[(size_t)v * 64 + tc * 4] = u.s;
        }
    }
}

// ---------------- CSR build ----------------
__global__ void hist_kernel(const int* __restrict__ src, const int* __restrict__ dst,
                            int* __restrict__ cnt, int E)
{
    int i = blockIdx.x * blockDim.x + threadIdx.x;
    const int stride = gridDim.x * blockDim.x;
    for (; i < E; i += stride) {
        atomicAdd(&cnt[dst[i]], 1);
        atomicAdd(&cnt[src[i]], 1);
    }
}

__global__ __launch_bounds__(256) void scan_a_kernel(
    const int* __restrict__ cnt, int* __restrict__ row, int* __restrict__ sums, int N)
{
    __shared__ int ls[256];
    const int t = threadIdx.x;
    const int base = blockIdx.x * 512;
    const int g0 = base + 2 * t, g1 = g0 + 1;
    const int x0 = (g0 < N) ? cnt[g0] : 0;
    const int x1 = (g1 < N) ? cnt[g1] : 0;
    const int s = x0 + x1;
    ls[t] = s;
    __syncthreads();
    #pragma unroll
    for (int off = 1; off < 256; off <<= 1) {
        int v = (t >= off) ? ls[t - off] : 0;
        __syncthreads();
        ls[t] += v;
        __syncthreads();
    }
    const int excl = ls[t] - s;
    if (g0 < N) row[g0] = excl;
    if (g1 < N) row[g1] = excl + x0;
    if (t == 255) sums[blockIdx.x] = ls[t];
}

__global__ __launch_bounds__(256) void scan_b_kernel(int* __restrict__ sums, int nb)
{
    __shared__ int ls[256];
    const int t = threadIdx.x;
    const int s = (t < nb) ? sums[t] : 0;
    ls[t] = s;
    __syncthreads();
    #pragma unroll
    for (int off = 1; off < 256; off <<= 1) {
        int v = (t >= off) ? ls[t - off] : 0;
        __syncthreads();
        ls[t] += v;
        __syncthreads();
    }
    if (t < nb) sums[t] = ls[t] - s;
}

__global__ void scan_c_kernel(int* __restrict__ row, int* __restrict__ ofs,
                              const int* __restrict__ sums, int2* __restrict__ inc,
                              int N, int total)
{
    const int i = blockIdx.x * blockDim.x + threadIdx.x;
    if (i < N) {
        const int r = row[i] + sums[i >> 9];
        row[i] = r;
        ofs[i] = r;
    }
    if (i == 0) {
        row[N] = total;
        // pad entries so reduce's unrolled masked loads read valid addresses
        inc[total + 0] = make_int2(0, 0);
        inc[total + 1] = make_int2(0, 0);
        inc[total + 2] = make_int2(0, 0);
        inc[total + 3] = make_int2(0, 0);
    }
}

__global__ void scatter_kernel(const int* __restrict__ src, const int* __restrict__ dst,
                               int* __restrict__ ofs, int2* __restrict__ inc, int E)
{
    int i = blockIdx.x * blockDim.x + threadIdx.x;
    const int stride = gridDim.x * blockDim.x;
    for (; i < E; i += stride) {
        const int s = src[i], d = dst[i];
        const int p = atomicAdd(&ofs[d], 1);
        inc[p] = make_int2(s, i);
        const int q = atomicAdd(&ofs[s], 1);
        inc[q] = make_int2(d, i);
    }
}

// ---------------- reduce: red[v] = sum leaky(A[u]+B[v]+C[e]) ----------------
// Unrolled x4: 8 independent 2B gathers in flight per wave iteration (~1 KB),
// masked tail via padded inc. MLP fix for R4's 1.46 TB/s effective.
__global__ __launch_bounds__(256) void reduce_kernel(
    const f16* __restrict__ A16, const f16* __restrict__ B16,
    const f16* __restrict__ C16, const int* __restrict__ row,
    const int2* __restrict__ inc, float* __restrict__ red, int N)
{
    const int lane = threadIdx.x & 63;
    const int gw = (blockIdx.x * blockDim.x + threadIdx.x) >> 6;
    const int W = (gridDim.x * blockDim.x) >> 6;
    for (int v = gw; v < N; v += W) {
        const float b = (float)B16[(size_t)v * 64 + lane];
        const int beg = row[v], end = row[v + 1];
        float acc = 0.f;
        for (int i = beg; i < end; i += 4) {
            const int2 r0 = inc[i];
            const int2 r1 = inc[i + 1];
            const int2 r2 = inc[i + 2];
            const int2 r3 = inc[i + 3];
            const float a0 = (float)A16[(size_t)r0.x * 64 + lane];
            const float c0 = (float)C16[(size_t)r0.y * 64 + lane];
            const float a1 = (float)A16[(size_t)r1.x * 64 + lane];
            const float c1 = (float)C16[(size_t)r1.y * 64 + lane];
            const float a2 = (float)A16[(size_t)r2.x * 64 + lane];
            const float c2 = (float)C16[(size_t)r2.y * 64 + lane];
            const float a3 = (float)A16[(size_t)r3.x * 64 + lane];
            const float c3 = (float)C16[(size_t)r3.y * 64 + lane];
            float m0 = a0 + b + c0; m0 = LEAKY(m0);
            float m1 = a1 + b + c1; m1 = LEAKY(m1);
            float m2 = a2 + b + c2; m2 = LEAKY(m2);
            float m3 = a3 + b + c3; m3 = LEAKY(m3);
            acc += m0;
            acc += (i + 1 < end) ? m1 : 0.f;
            acc += (i + 2 < end) ? m2 : 0.f;
            acc += (i + 3 < end) ? m3 : 0.f;
        }
        red[(size_t)v * 64 + lane] = acc;
    }
}

// ---------------- apply: out = leaky([nf|red] @ WT_n), tile 128x64, K=128 ----------------
__global__ __launch_bounds__(256) void apply_kernel(
    const float4* __restrict__ nf4, const float4* __restrict__ red4,
    const float* __restrict__ WT, float* __restrict__ out, int M)
{
    __shared__ float As[64 * 128];
    __shared__ float Ws[128 * 64];
    const int t = threadIdx.x;
    const int tr = t >> 4, tc = t & 15;
    const int m0 = blockIdx.x * 128;

    #pragma unroll
    for (int i = 0; i < 8; ++i)
        ((float4*)Ws)[t + 256 * i] = ((const float4*)WT)[t + 256 * i];

    float acc[8][4];
    #pragma unroll
    for (int ri = 0; ri < 8; ++ri)
        #pragma unroll
        for (int ci = 0; ci < 4; ++ci) acc[ri][ci] = 0.f;

    for (int h = 0; h < 2; ++h) {
        const float4* __restrict__ src = h ? red4 : nf4;
        #pragma unroll
        for (int i = 0; i < 8; ++i) {
            const int idx = t + 256 * i;
            const int m = idx >> 4, kq = idx & 15;
            float4 v = make_float4(0.f, 0.f, 0.f, 0.f);
            if (m0 + m < M) v = src[(size_t)(m0 + m) * 16 + kq];
            As[swz(4 * kq + 0, m)] = v.x;
            As[swz(4 * kq + 1, m)] = v.y;
            As[swz(4 * kq + 2, m)] = v.z;
            As[swz(4 * kq + 3, m)] = v.w;
        }
        __syncthreads();
        #pragma unroll 8
        for (int k = 0; k < 64; ++k) {
            const float4 aLo = *(const float4*)&As[swz(k, tr * 4)];
            const float4 aHi = *(const float4*)&As[swz(k, 64 + tr * 4)];
            const float4 w  = *(const float4*)&Ws[(h * 64 + k) * 64 + tc * 4];
            const float av[8] = {aLo.x, aLo.y, aLo.z, aLo.w, aHi.x, aHi.y, aHi.z, aHi.w};
            const float bv[4] = {w.x, w.y, w.z, w.w};
            #pragma unroll
            for (int ri = 0; ri < 8; ++ri)
                #pragma unroll
                for (int ci = 0; ci < 4; ++ci) acc[ri][ci] += av[ri] * bv[ci];
        }
        __syncthreads();
    }

    #pragma unroll
    for (int ri = 0; ri < 8; ++ri) {
        const int v = m0 + ((ri < 4) ? (tr * 4 + ri) : (64 + tr * 4 + ri - 4));
        if (v < M) {
            float4 o;
            o.x = LEAKY(acc[ri][0]); o.y = LEAKY(acc[ri][1]);
            o.z = LEAKY(acc[ri][2]); o.w = LEAKY(acc[ri][3]);
            *(float4*)&out[(size_t)v * 64 + tc * 4] = o;
        }
    }
}

extern "C" void kernel_launch(void* const* d_in, const int* in_sizes, int n_in,
                              void* d_out, int out_size, void* d_ws, size_t ws_size,
                              hipStream_t stream) {
    const float* nf  = (const float*)d_in[0];   // [N,64]
    const float* ef  = (const float*)d_in[1];   // [E,32]
    const int*   src = (const int*)d_in[2];     // [E]
    const int*   dst = (const int*)d_in[3];     // [E]
    const float* We  = (const float*)d_in[4];   // [64,160]
    const float* Wn  = (const float*)d_in[5];   // [64,128]

    const int N = in_sizes[0] / 64;
    const int E = in_sizes[2];

    char* p = (char*)d_ws;
    auto alloc = [&](size_t bytes) -> char* {
        char* r = p; p += (bytes + 255) & ~(size_t)255; return r;
    };
    float* red  = (float*)alloc((size_t)N * 64 * 4);
    float* WTab = (float*)alloc(8192 * 4);
    float* WTc  = (float*)alloc(2048 * 4);
    float* WTn  = (float*)alloc(8192 * 4);
    int2*  inc  = (int2*)alloc(((size_t)2 * E + 4) * 8);
    int*   cnt  = (int*)alloc((size_t)N * 4);
    int*   row  = (int*)alloc(((size_t)N + 1) * 4);
    int*   sums = (int*)alloc(256 * 4);
    int*   ofs  = (int*)alloc((size_t)N * 4);
    f16*   A16  = (f16*)alloc((size_t)N * 64 * 2);
    f16*   B16  = (f16*)alloc((size_t)N * 64 * 2);
    f16*   C16  = (f16*)alloc((size_t)E * 64 * 2);

    hipMemsetAsync(cnt, 0, (size_t)N * sizeof(int), stream);
    prep_weights_kernel<<<36, 256, 0, stream>>>(We, Wn, WTab, WTc, WTn);
    gemm_ab_kernel<<<(N + 127) / 128, 256, 0, stream>>>((const float4*)nf, WTab, A16, B16, N);
    gemm_c_kernel<<<(E + 127) / 128, 256, 0, stream>>>((const float4*)ef, WTc, C16, E);
    hist_kernel<<<2048, 256, 0, stream>>>(src, dst, cnt, E);
    const int nb = (N + 511) / 512;
    scan_a_kernel<<<nb, 256, 0, stream>>>(cnt, row, sums, N);
    scan_b_kernel<<<1, 256, 0, stream>>>(sums, nb);
    scan_c_kernel<<<(N + 255) / 256, 256, 0, stream>>>(row, ofs, sums, inc, N, 2 * E);
    scatter_kernel<<<2048, 256, 0, stream>>>(src, dst, ofs, inc, E);
    reduce_kernel<<<4096, 256, 0, stream>>>(A16, B16, C16, row, inc, red, N);
    apply_kernel<<<(N + 127) / 128, 256, 0, stream>>>((const float4*)nf, (const float4*)red,
                                                      WTn, (float*)d_out, N);
}

// Round 6
// 361.971 us; speedup vs baseline: 2.1653x; 1.0523x over previous
//
#include <hip/hip_runtime.h>
#include <stdint.h>

// GNN layer, fp32, GEMM-restructured + CSR reduce:
//   prep: transpose weights into WT_ab[64][128], WT_c[32][64], WT_n[128][64]
//   gemm_ab: [A16|B16] = nf @ We[:,0:128]^T          (fp16 out, [N,64] each)
//   gemm_c:  C16 = ef @ We[:,128:160]^T              (fp16 out, [E,64])
//   CSR build: hist -> scan -> scatter, XCD-partitioned (blockIdx&7 owns a
//     node range; all stores/atomics for a line come from one XCD -> kills
//     the 8x partial-line writeback amplification measured in R5)
//   reduce:  red[v] = sum leaky(A16[u] + B16[v] + C16[e])   (fp32, x4 unroll)
//   apply:   out = leaky(nf @ Wn[:,0:64]^T + red @ Wn[:,64:128]^T)

#define LEAKY(x) ((x) > 0.0f ? (x) : 0.01f * (x))
typedef _Float16 f16;

static __device__ __forceinline__ int swz(int k, int c) {
    return k * 128 + (c ^ (((k >> 2) & 7) << 2));
}

union H4 { f16 h[4]; short4 s; };

// ---------------- weight prep (transpose into ws) ----------------
__global__ void prep_weights_kernel(const float* __restrict__ We,
                                    const float* __restrict__ Wn,
                                    float* __restrict__ WTab,
                                    float* __restrict__ WTc,
                                    float* __restrict__ WTn)
{
    int i = blockIdx.x * blockDim.x + threadIdx.x;
    const int stride = gridDim.x * blockDim.x;
    for (; i < 8192 + 2048 + 8192; i += stride) {
        if (i < 8192) {
            int k = i >> 7, n = i & 127;
            WTab[i] = We[(n & 63) * 160 + (n >> 6) * 64 + k];
        } else if (i < 10240) {
            int j = i - 8192; int k = j >> 6, n = j & 63;
            WTc[j] = We[n * 160 + 128 + k];
        } else {
            int j = i - 10240; int k = j >> 6, n = j & 63;
            WTn[j] = Wn[n * 128 + k];
        }
    }
}

// ---------------- gemm_ab: [A|B] = nf @ WT_ab, tile 128x128, K=64 ----------------
__global__ __launch_bounds__(256) void gemm_ab_kernel(
    const float4* __restrict__ nf4, const float* __restrict__ WT,
    f16* __restrict__ A16, f16* __restrict__ B16, int M)
{
    __shared__ float As[64 * 128];
    __shared__ float Ws[64 * 128];
    const int t = threadIdx.x;
    const int tr = t >> 4, tc = t & 15;
    const int m0 = blockIdx.x * 128;

    #pragma unroll
    for (int i = 0; i < 8; ++i)
        ((float4*)Ws)[t + 256 * i] = ((const float4*)WT)[t + 256 * i];
    #pragma unroll
    for (int i = 0; i < 8; ++i) {
        const int idx = t + 256 * i;
        const int m = idx >> 4, kq = idx & 15;
        float4 v = make_float4(0.f, 0.f, 0.f, 0.f);
        if (m0 + m < M) v = nf4[(size_t)(m0 + m) * 16 + kq];
        As[swz(4 * kq + 0, m)] = v.x;
        As[swz(4 * kq + 1, m)] = v.y;
        As[swz(4 * kq + 2, m)] = v.z;
        As[swz(4 * kq + 3, m)] = v.w;
    }
    __syncthreads();

    float acc[8][8];
    #pragma unroll
    for (int ri = 0; ri < 8; ++ri)
        #pragma unroll
        for (int ci = 0; ci < 8; ++ci) acc[ri][ci] = 0.f;

    #pragma unroll 8
    for (int k = 0; k < 64; ++k) {
        const float4 aLo = *(const float4*)&As[swz(k, tr * 4)];
        const float4 aHi = *(const float4*)&As[swz(k, 64 + tr * 4)];
        const float4 bLo = *(const float4*)&Ws[k * 128 + tc * 4];
        const float4 bHi = *(const float4*)&Ws[k * 128 + 64 + tc * 4];
        const float av[8] = {aLo.x, aLo.y, aLo.z, aLo.w, aHi.x, aHi.y, aHi.z, aHi.w};
        const float bv[8] = {bLo.x, bLo.y, bLo.z, bLo.w, bHi.x, bHi.y, bHi.z, bHi.w};
        #pragma unroll
        for (int ri = 0; ri < 8; ++ri)
            #pragma unroll
            for (int ci = 0; ci < 8; ++ci) acc[ri][ci] += av[ri] * bv[ci];
    }

    #pragma unroll
    for (int ri = 0; ri < 8; ++ri) {
        const int v = m0 + ((ri < 4) ? (tr * 4 + ri) : (64 + tr * 4 + ri - 4));
        if (v < M) {
            H4 lo, hi;
            #pragma unroll
            for (int j = 0; j < 4; ++j) { lo.h[j] = (f16)acc[ri][j]; hi.h[j] = (f16)acc[ri][4 + j]; }
            *(short4*)&A16[(size_t)v * 64 + tc * 4] = lo.s;
            *(short4*)&B16[(size_t)v * 64 + tc * 4] = hi.s;
        }
    }
}

// ---------------- gemm_c: C = ef @ WT_c, tile 128x64, K=32 ----------------
__global__ __launch_bounds__(256) void gemm_c_kernel(
    const float4* __restrict__ ef4, const float* __restrict__ WT,
    f16* __restrict__ C16, int M)
{
    __shared__ float As[32 * 128];
    __shared__ float Ws[32 * 64];
    const int t = threadIdx.x;
    const int tr = t >> 4, tc = t & 15;
    const int m0 = blockIdx.x * 128;

    #pragma unroll
    for (int i = 0; i < 2; ++i)
        ((float4*)Ws)[t + 256 * i] = ((const float4*)WT)[t + 256 * i];
    #pragma unroll
    for (int i = 0; i < 4; ++i) {
        const int idx = t + 256 * i;
        const int m = idx >> 3, kq = idx & 7;
        float4 v = make_float4(0.f, 0.f, 0.f, 0.f);
        if (m0 + m < M) v = ef4[(size_t)(m0 + m) * 8 + kq];
        As[swz(4 * kq + 0, m)] = v.x;
        As[swz(4 * kq + 1, m)] = v.y;
        As[swz(4 * kq + 2, m)] = v.z;
        As[swz(4 * kq + 3, m)] = v.w;
    }
    __syncthreads();

    float acc[8][4];
    #pragma unroll
    for (int ri = 0; ri < 8; ++ri)
        #pragma unroll
        for (int ci = 0; ci < 4; ++ci) acc[ri][ci] = 0.f;

    #pragma unroll 8
    for (int k = 0; k < 32; ++k) {
        const float4 aLo = *(const float4*)&As[swz(k, tr * 4)];
        const float4 aHi = *(const float4*)&As[swz(k, 64 + tr * 4)];
        const float4 w  = *(const float4*)&Ws[k * 64 + tc * 4];
        const float av[8] = {aLo.x, aLo.y, aLo.z, aLo.w, aHi.x, aHi.y, aHi.z, aHi.w};
        const float bv[4] = {w.x, w.y, w.z, w.w};
        #pragma unroll
        for (int ri = 0; ri < 8; ++ri)
            #pragma unroll
            for (int ci = 0; ci < 4; ++ci) acc[ri][ci] += av[ri] * bv[ci];
    }

    #pragma unroll
    for (int ri = 0; ri < 8; ++ri) {
        const int v = m0 + ((ri < 4) ? (tr * 4 + ri) : (64 + tr * 4 + ri - 4));
        if (v < M) {
            H4 u;
            #pragma unroll
            for (int j = 0; j < 4; ++j) u.h[j] = (f16)acc[ri][j];
            *(short4*)&C16[(size_t)v * 64 + tc * 4] = u.s;
        }
    }
}

// ---------------- CSR build (XCD-partitioned) ----------------
// blockIdx&7 = partition p owns nodes [N*p/8, N*(p+1)/8). Each partition
// grid-strides the whole edge list (re-reads are LLC-resident).
__global__ __launch_bounds__(256) void hist_kernel(
    const int* __restrict__ src, const int* __restrict__ dst,
    int* __restrict__ cnt, int E, int N)
{
    const int part = blockIdx.x & 7;
    const int lo = (int)(((long long)N * part) >> 3);
    const int hi = (int)(((long long)N * (part + 1)) >> 3);
    const int tid = (blockIdx.x >> 3) * blockDim.x + threadIdx.x;
    const int tpp = (gridDim.x >> 3) * blockDim.x;
    const int E4 = E >> 2;
    const int4* src4 = (const int4*)src;
    const int4* dst4 = (const int4*)dst;
    for (int j = tid; j < E4; j += tpp) {
        const int4 s = src4[j], d = dst4[j];
        if (d.x >= lo && d.x < hi) atomicAdd(&cnt[d.x], 1);
        if (d.y >= lo && d.y < hi) atomicAdd(&cnt[d.y], 1);
        if (d.z >= lo && d.z < hi) atomicAdd(&cnt[d.z], 1);
        if (d.w >= lo && d.w < hi) atomicAdd(&cnt[d.w], 1);
        if (s.x >= lo && s.x < hi) atomicAdd(&cnt[s.x], 1);
        if (s.y >= lo && s.y < hi) atomicAdd(&cnt[s.y], 1);
        if (s.z >= lo && s.z < hi) atomicAdd(&cnt[s.z], 1);
        if (s.w >= lo && s.w < hi) atomicAdd(&cnt[s.w], 1);
    }
    for (int i = (E4 << 2) + tid; i < E; i += tpp) {
        const int s = src[i], d = dst[i];
        if (d >= lo && d < hi) atomicAdd(&cnt[d], 1);
        if (s >= lo && s < hi) atomicAdd(&cnt[s], 1);
    }
}

__global__ __launch_bounds__(256) void scan_a_kernel(
    const int* __restrict__ cnt, int* __restrict__ row, int* __restrict__ sums, int N)
{
    __shared__ int ls[256];
    const int t = threadIdx.x;
    const int base = blockIdx.x * 512;
    const int g0 = base + 2 * t, g1 = g0 + 1;
    const int x0 = (g0 < N) ? cnt[g0] : 0;
    const int x1 = (g1 < N) ? cnt[g1] : 0;
    const int s = x0 + x1;
    ls[t] = s;
    __syncthreads();
    #pragma unroll
    for (int off = 1; off < 256; off <<= 1) {
        int v = (t >= off) ? ls[t - off] : 0;
        __syncthreads();
        ls[t] += v;
        __syncthreads();
    }
    const int excl = ls[t] - s;
    if (g0 < N) row[g0] = excl;
    if (g1 < N) row[g1] = excl + x0;
    if (t == 255) sums[blockIdx.x] = ls[t];
}

__global__ __launch_bounds__(256) void scan_b_kernel(int* __restrict__ sums, int nb)
{
    __shared__ int ls[256];
    const int t = threadIdx.x;
    const int s = (t < nb) ? sums[t] : 0;
    ls[t] = s;
    __syncthreads();
    #pragma unroll
    for (int off = 1; off < 256; off <<= 1) {
        int v = (t >= off) ? ls[t - off] : 0;
        __syncthreads();
        ls[t] += v;
        __syncthreads();
    }
    if (t < nb) sums[t] = ls[t] - s;
}

__global__ void scan_c_kernel(int* __restrict__ row, int* __restrict__ ofs,
                              const int* __restrict__ sums, int2* __restrict__ inc,
                              int N, int total)
{
    const int i = blockIdx.x * blockDim.x + threadIdx.x;
    if (i < N) {
        const int r = row[i] + sums[i >> 9];
        row[i] = r;
        ofs[i] = r;
    }
    if (i == 0) {
        row[N] = total;
        inc[total + 0] = make_int2(0, 0);
        inc[total + 1] = make_int2(0, 0);
        inc[total + 2] = make_int2(0, 0);
        inc[total + 3] = make_int2(0, 0);
    }
}

__global__ __launch_bounds__(256) void scatter_kernel(
    const int* __restrict__ src, const int* __restrict__ dst,
    int* __restrict__ ofs, int2* __restrict__ inc, int E, int N)
{
    const int part = blockIdx.x & 7;
    const int lo = (int)(((long long)N * part) >> 3);
    const int hi = (int)(((long long)N * (part + 1)) >> 3);
    const int tid = (blockIdx.x >> 3) * blockDim.x + threadIdx.x;
    const int tpp = (gridDim.x >> 3) * blockDim.x;
    const int E4 = E >> 2;
    const int4* src4 = (const int4*)src;
    const int4* dst4 = (const int4*)dst;
    for (int j = tid; j < E4; j += tpp) {
        const int4 s = src4[j], d = dst4[j];
        const int e0 = 4 * j;
        if (d.x >= lo && d.x < hi) { const int p = atomicAdd(&ofs[d.x], 1); inc[p] = make_int2(s.x, e0 + 0); }
        if (d.y >= lo && d.y < hi) { const int p = atomicAdd(&ofs[d.y], 1); inc[p] = make_int2(s.y, e0 + 1); }
        if (d.z >= lo && d.z < hi) { const int p = atomicAdd(&ofs[d.z], 1); inc[p] = make_int2(s.z, e0 + 2); }
        if (d.w >= lo && d.w < hi) { const int p = atomicAdd(&ofs[d.w], 1); inc[p] = make_int2(s.w, e0 + 3); }
        if (s.x >= lo && s.x < hi) { const int q = atomicAdd(&ofs[s.x], 1); inc[q] = make_int2(d.x, e0 + 0); }
        if (s.y >= lo && s.y < hi) { const int q = atomicAdd(&ofs[s.y], 1); inc[q] = make_int2(d.y, e0 + 1); }
        if (s.z >= lo && s.z < hi) { const int q = atomicAdd(&ofs[s.z], 1); inc[q] = make_int2(d.z, e0 + 2); }
        if (s.w >= lo && s.w < hi) { const int q = atomicAdd(&ofs[s.w], 1); inc[q] = make_int2(d.w, e0 + 3); }
    }
    for (int i = (E4 << 2) + tid; i < E; i += tpp) {
        const int s = src[i], d = dst[i];
        if (d >= lo && d < hi) { const int p = atomicAdd(&ofs[d], 1); inc[p] = make_int2(s, i); }
        if (s >= lo && s < hi) { const int q = atomicAdd(&ofs[s], 1); inc[q] = make_int2(d, i); }
    }
}

// ---------------- reduce: red[v] = sum leaky(A[u]+B[v]+C[e]) ----------------
__global__ __launch_bounds__(256) void reduce_kernel(
    const f16* __restrict__ A16, const f16* __restrict__ B16,
    const f16* __restrict__ C16, const int* __restrict__ row,
    const int2* __restrict__ inc, float* __restrict__ red, int N)
{
    const int lane = threadIdx.x & 63;
    const int gw = (blockIdx.x * blockDim.x + threadIdx.x) >> 6;
    const int W = (gridDim.x * blockDim.x) >> 6;
    for (int v = gw; v < N; v += W) {
        const float b = (float)B16[(size_t)v * 64 + lane];
        const int beg = row[v], end = row[v + 1];
        float acc = 0.f;
        for (int i = beg; i < end; i += 4) {
            const int2 r0 = inc[i];
            const int2 r1 = inc[i + 1];
            const int2 r2 = inc[i + 2];
            const int2 r3 = inc[i + 3];
            const float a0 = (float)A16[(size_t)r0.x * 64 + lane];
            const float c0 = (float)C16[(size_t)r0.y * 64 + lane];
            const float a1 = (float)A16[(size_t)r1.x * 64 + lane];
            const float c1 = (float)C16[(size_t)r1.y * 64 + lane];
            const float a2 = (float)A16[(size_t)r2.x * 64 + lane];
            const float c2 = (float)C16[(size_t)r2.y * 64 + lane];
            const float a3 = (float)A16[(size_t)r3.x * 64 + lane];
            const float c3 = (float)C16[(size_t)r3.y * 64 + lane];
            float m0 = a0 + b + c0; m0 = LEAKY(m0);
            float m1 = a1 + b + c1; m1 = LEAKY(m1);
            float m2 = a2 + b + c2; m2 = LEAKY(m2);
            float m3 = a3 + b + c3; m3 = LEAKY(m3);
            acc += m0;
            acc += (i + 1 < end) ? m1 : 0.f;
            acc += (i + 2 < end) ? m2 : 0.f;
            acc += (i + 3 < end) ? m3 : 0.f;
        }
        red[(size_t)v * 64 + lane] = acc;
    }
}

// ---------------- apply: out = leaky([nf|red] @ WT_n), tile 128x64, K=128 ----------------
__global__ __launch_bounds__(256) void apply_kernel(
    const float4* __restrict__ nf4, const float4* __restrict__ red4,
    const float* __restrict__ WT, float* __restrict__ out, int M)
{
    __shared__ float As[64 * 128];
    __shared__ float Ws[128 * 64];
    const int t = threadIdx.x;
    const int tr = t >> 4, tc = t & 15;
    const int m0 = blockIdx.x * 128;

    #pragma unroll
    for (int i = 0; i < 8; ++i)
        ((float4*)Ws)[t + 256 * i] = ((const float4*)WT)[t + 256 * i];

    float acc[8][4];
    #pragma unroll
    for (int ri = 0; ri < 8; ++ri)
        #pragma unroll
        for (int ci = 0; ci < 4; ++ci) acc[ri][ci] = 0.f;

    for (int h = 0; h < 2; ++h) {
        const float4* __restrict__ src = h ? red4 : nf4;
        #pragma unroll
        for (int i = 0; i < 8; ++i) {
            const int idx = t + 256 * i;
            const int m = idx >> 4, kq = idx & 15;
            float4 v = make_float4(0.f, 0.f, 0.f, 0.f);
            if (m0 + m < M) v = src[(size_t)(m0 + m) * 16 + kq];
            As[swz(4 * kq + 0, m)] = v.x;
            As[swz(4 * kq + 1, m)] = v.y;
            As[swz(4 * kq + 2, m)] = v.z;
            As[swz(4 * kq + 3, m)] = v.w;
        }
        __syncthreads();
        #pragma unroll 8
        for (int k = 0; k < 64; ++k) {
            const float4 aLo = *(const float4*)&As[swz(k, tr * 4)];
            const float4 aHi = *(const float4*)&As[swz(k, 64 + tr * 4)];
            const float4 w  = *(const float4*)&Ws[(h * 64 + k) * 64 + tc * 4];
            const float av[8] = {aLo.x, aLo.y, aLo.z, aLo.w, aHi.x, aHi.y, aHi.z, aHi.w};
            const float bv[4] = {w.x, w.y, w.z, w.w};
            #pragma unroll
            for (int ri = 0; ri < 8; ++ri)
                #pragma unroll
                for (int ci = 0; ci < 4; ++ci) acc[ri][ci] += av[ri] * bv[ci];
        }
        __syncthreads();
    }

    #pragma unroll
    for (int ri = 0; ri < 8; ++ri) {
        const int v = m0 + ((ri < 4) ? (tr * 4 + ri) : (64 + tr * 4 + ri - 4));
        if (v < M) {
            float4 o;
            o.x = LEAKY(acc[ri][0]); o.y = LEAKY(acc[ri][1]);
            o.z = LEAKY(acc[ri][2]); o.w = LEAKY(acc[ri][3]);
            *(float4*)&out[(size_t)v * 64 + tc * 4] = o;
        }
    }
}

extern "C" void kernel_launch(void* const* d_in, const int* in_sizes, int n_in,
                              void* d_out, int out_size, void* d_ws, size_t ws_size,
                              hipStream_t stream) {
    const float* nf  = (const float*)d_in[0];   // [N,64]
    const float* ef  = (const float*)d_in[1];   // [E,32]
    const int*   src = (const int*)d_in[2];     // [E]
    const int*   dst = (const int*)d_in[3];     // [E]
    const float* We  = (const float*)d_in[4];   // [64,160]
    const float* Wn  = (const float*)d_in[5];   // [64,128]

    const int N = in_sizes[0] / 64;
    const int E = in_sizes[2];

    char* p = (char*)d_ws;
    auto alloc = [&](size_t bytes) -> char* {
        char* r = p; p += (bytes + 255) & ~(size_t)255; return r;
    };
    float* red  = (float*)alloc((size_t)N * 64 * 4);
    float* WTab = (float*)alloc(8192 * 4);
    float* WTc  = (float*)alloc(2048 * 4);
    float* WTn  = (float*)alloc(8192 * 4);
    int2*  inc  = (int2*)alloc(((size_t)2 * E + 4) * 8);
    int*   cnt  = (int*)alloc((size_t)N * 4);
    int*   row  = (int*)alloc(((size_t)N + 1) * 4);
    int*   sums = (int*)alloc(256 * 4);
    int*   ofs  = (int*)alloc((size_t)N * 4);
    f16*   A16  = (f16*)alloc((size_t)N * 64 * 2);
    f16*   B16  = (f16*)alloc((size_t)N * 64 * 2);
    f16*   C16  = (f16*)alloc((size_t)E * 64 * 2);

    hipMemsetAsync(cnt, 0, (size_t)N * sizeof(int), stream);
    prep_weights_kernel<<<36, 256, 0, stream>>>(We, Wn, WTab, WTc, WTn);
    gemm_ab_kernel<<<(N + 127) / 128, 256, 0, stream>>>((const float4*)nf, WTab, A16, B16, N);
    gemm_c_kernel<<<(E + 127) / 128, 256, 0, stream>>>((const float4*)ef, WTc, C16, E);
    hist_kernel<<<2048, 256, 0, stream>>>(src, dst, cnt, E, N);
    const int nb = (N + 511) / 512;
    scan_a_kernel<<<nb, 256, 0, stream>>>(cnt, row, sums, N);
    scan_b_kernel<<<1, 256, 0, stream>>>(sums, nb);
    scan_c_kernel<<<(N + 255) / 256, 256, 0, stream>>>(row, ofs, sums, inc, N, 2 * E);
    scatter_kernel<<<2048, 256, 0, stream>>>(src, dst, ofs, inc, E, N);
    reduce_kernel<<<4096, 256, 0, stream>>>(A16, B16, C16, row, inc, red, N);
    apply_kernel<<<(N + 127) / 128, 256, 0, stream>>>((const float4*)nf, (const float4*)red,
                                                      WTn, (float*)d_out, N);
}